// Round 7
// baseline (196.136 us; speedup 1.0000x reference)
//
#include <hip/hip_runtime.h>

#define DDIM 2048
#define BDIM 2048
#define EPS 1e-7f
#define DTILE 16                 // d per wave-job
#define DSLICE 4                 // d staged per slice
#define NSLICE (DTILE / DSLICE)
#define GATE_BYTES (DDIM * 64 * sizeof(float))

typedef float f32x4 __attribute__((ext_vector_type(4)));  // native vec for nontemporal

// ---- kernel 1: gate[d][i] = sigmoid(50 * lut[d][i]) (512 KB, L2-resident) ----
__global__ __launch_bounds__(256)
void gate_kernel(const float* __restrict__ lut, float* __restrict__ gate) {
    const int i = blockIdx.x * 256 + threadIdx.x;          // float4 index
    float4 v = reinterpret_cast<const float4*>(lut)[i];
    float4 r;
    r.x = 1.0f / (1.0f + __expf(-50.0f * v.x));
    r.y = 1.0f / (1.0f + __expf(-50.0f * v.y));
    r.z = 1.0f / (1.0f + __expf(-50.0f * v.z));
    r.w = 1.0f / (1.0f + __expf(-50.0f * v.w));
    reinterpret_cast<float4*>(gate)[i] = r;
}

// ---- kernel 2: lane = b, loop over d. Gate row is wave-uniform per d-iter
// (scalar/L1-broadcast loads, 4 floats at a time: NO per-thread g[64]).
// Single-wave blocks: no __syncthreads anywhere. Inputs staged per-slice into
// LDS via flat 16B-granule coalesced loads + granule rotation; outputs
// transposed through a swizzled 4KB LDS tile -> dense coalesced stores.
template <bool PRE>
__global__ __launch_bounds__(64, 4)
void lut_main(const float* __restrict__ inputs,
              const float* __restrict__ gsrc,   // gate (PRE) or lut (!PRE)
              float* __restrict__ out) {
    __shared__ float slds[64 * 24];   // [64 b][4 d][6 f], granule-rotated (6 KB)
    __shared__ float olds[64 * 16];   // [64 b][16 d], col-swizzled (4 KB)

    const int l  = threadIdx.x;                 // lane = b within chunk
    const int b0 = blockIdx.x * 64;             // 32 b-chunks
    const int d0 = blockIdx.y * DTILE;          // 128 d-chunks

    // Granule-rotation table: P[g] = ((g + l) % 6) * 4 float-offset.
    // Indexed only by unroll constants below -> stays in registers.
    const int lm6 = l - 6 * ((l * 10923) >> 16);            // l % 6
    int P[6];
#pragma unroll
    for (int g = 0; g < 6; ++g) {
        int t = g + lm6; if (t >= 6) t -= 6;
        P[g] = t * 4;
    }
    const int lbase = l * 24;

    float4 pf[6];

    // Stage-load slice s: flat 16B granules over [64 rows][96 B] -> coalesced.
    auto LOADS = [&](int s) {
#pragma unroll
        for (int r = 0; r < 6; ++r) {
            const int idx  = r * 64 + l;                    // [0,384)
            const int brow = (idx * 10923) >> 16;           // idx / 6 (exact)
            const int g16  = idx - brow * 6;                // granule in row
            const size_t off = (size_t)(b0 + brow) * (DDIM * 6)
                             + (size_t)(d0 + s * DSLICE) * 6 + g16 * 4;
            pf[r] = *reinterpret_cast<const float4*>(inputs + off);
        }
    };
    // LDS write with per-row granule rotation (matches P[] on the read side).
    auto WRITES = [&]() {
#pragma unroll
        for (int r = 0; r < 6; ++r) {
            const int idx  = r * 64 + l;
            const int brow = (idx * 10923) >> 16;
            const int g16  = idx - brow * 6;
            const int bm6  = brow - 6 * ((brow * 10923) >> 16);
            int rot = g16 + bm6; if (rot >= 6) rot -= 6;
            *reinterpret_cast<float4*>(&slds[brow * 24 + rot * 4]) = pf[r];
        }
    };

    LOADS(0);

#pragma unroll
    for (int s = 0; s < NSLICE; ++s) {
        WRITES();                                 // vmcnt wait handled by compiler
        if (s + 1 < NSLICE) LOADS(s + 1);         // prefetch flies under compute

#pragma unroll
        for (int dd = 0; dd < DSLICE; ++dd) {
            // 6 inputs for (b = b0+l, d = d0+s*4+dd) from rotated granules
            float x[6];
#pragma unroll
            for (int j = 0; j < 6; ++j) {
                const int q = dd * 6 + j;         // unroll-constant
                x[j] = slds[lbase + P[q >> 2] + (q & 3)];
            }

            // p_q = relu(concat(1-x, x)) + eps; hi_j selected when MSB-first
            // bit j of i is 1 (validated rounds 1-4).
            float lo0 = fmaxf(x[0], 0.f) + EPS, hi0 = fmaxf(1.f - x[0], 0.f) + EPS;
            float lo1 = fmaxf(x[1], 0.f) + EPS, hi1 = fmaxf(1.f - x[1], 0.f) + EPS;
            float lo2 = fmaxf(x[2], 0.f) + EPS, hi2 = fmaxf(1.f - x[2], 0.f) + EPS;
            float lo3 = fmaxf(x[3], 0.f) + EPS, hi3 = fmaxf(1.f - x[3], 0.f) + EPS;
            float lo4 = fmaxf(x[4], 0.f) + EPS, hi4 = fmaxf(1.f - x[4], 0.f) + EPS;
            float lo5 = fmaxf(x[5], 0.f) + EPS, hi5 = fmaxf(1.f - x[5], 0.f) + EPS;

            float m01[4] = {lo0 * lo1, lo0 * hi1, hi0 * lo1, hi0 * hi1};
            float m23[4] = {lo2 * lo3, lo2 * hi3, hi2 * lo3, hi2 * hi3};
            float m45[4] = {lo4 * lo5, lo4 * hi5, hi4 * lo5, hi4 * hi5};

            // Gate row for this d: wave-uniform address -> scalar/L1 broadcast.
            const float* gr = gsrc + (size_t)(d0 + s * DSLICE + dd) * 64;

            float acc = 0.f;
#pragma unroll
            for (int p = 0; p < 4; ++p) {
                float accp = 0.f;
#pragma unroll
                for (int q4 = 0; q4 < 4; ++q4) {
                    float4 gv = *reinterpret_cast<const float4*>(gr + (p * 4 + q4) * 4);
                    if (!PRE) {   // fallback: inline sigmoid (uniform values)
                        gv.x = 1.0f / (1.0f + __expf(-50.0f * gv.x));
                        gv.y = 1.0f / (1.0f + __expf(-50.0f * gv.y));
                        gv.z = 1.0f / (1.0f + __expf(-50.0f * gv.z));
                        gv.w = 1.0f / (1.0f + __expf(-50.0f * gv.w));
                    }
                    float inner = m45[0] * gv.x;
                    inner = fmaf(m45[1], gv.y, inner);
                    inner = fmaf(m45[2], gv.z, inner);
                    inner = fmaf(m45[3], gv.w, inner);
                    accp = fmaf(m23[q4], inner, accp);
                }
                acc = fmaf(m01[p], accp, acc);
            }

            const int c = s * DSLICE + dd;
            olds[l * 16 + ((c + l) & 15)] = acc;  // col-swizzle by owning lane
        }
    }

    // Write out the [64 b][16 d] tile: dense, coalesced 16B rows.
#pragma unroll
    for (int k = 0; k < 4; ++k) {
        const int rho = k * 16 + (l >> 2);        // b-row within chunk
        const int cb  = (l & 3) * 4;              // d-col base
        f32x4 o;
        o.x = olds[rho * 16 + ((cb + 0 + rho) & 15)];
        o.y = olds[rho * 16 + ((cb + 1 + rho) & 15)];
        o.z = olds[rho * 16 + ((cb + 2 + rho) & 15)];
        o.w = olds[rho * 16 + ((cb + 3 + rho) & 15)];
        __builtin_nontemporal_store(o, reinterpret_cast<f32x4*>(
            out + (size_t)(b0 + rho) * DDIM + d0 + cb));
    }
}

extern "C" void kernel_launch(void* const* d_in, const int* in_sizes, int n_in,
                              void* d_out, int out_size, void* d_ws, size_t ws_size,
                              hipStream_t stream) {
    const float* inputs = (const float*)d_in[0];
    const float* lut    = (const float*)d_in[1];
    // d_in[2] (p_q_2_lut_table) is a deterministic bit-selection table whose
    // structure is folded into the product tree above.
    float* out = (float*)d_out;

    dim3 grid(BDIM / 64, DDIM / DTILE);   // (32, 128) = 4096 one-wave blocks
    dim3 block(64);

    if (ws_size >= GATE_BYTES) {
        float* gate = (float*)d_ws;
        gate_kernel<<<dim3(DDIM * 64 / 4 / 256), dim3(256), 0, stream>>>(lut, gate);
        lut_main<true><<<grid, block, 0, stream>>>(inputs, gate, out);
    } else {
        lut_main<false><<<grid, block, 0, stream>>>(inputs, lut, out);
    }
}